// Round 1
// baseline (1211.946 us; speedup 1.0000x reference)
//
#include <hip/hip_runtime.h>

// GCN layer: out = relu( (segment_mean(feature[edge_src], edge_dst)) @ W^T + b )
// N=100000 nodes, E=1200000 edges, 64 feats in/out, all f32.

constexpr int kNodes = 100000;
constexpr int kEdges = 1200000;
constexpr int kFeats = 64;

// ---------------------------------------------------------------------------
// Kernel 1: edge-parallel scatter-add.
// 16 lanes per edge; each lane handles one float4 (16 B) of the 256 B source
// row. Gather read is fully coalesced per edge; accumulation via global
// (device-scope) f32 atomics into d_out acting as the sum buffer.
// ---------------------------------------------------------------------------
__global__ __launch_bounds__(256) void gcn_scatter(
    const float4* __restrict__ feat4,   // [kNodes*16] float4 view of feature
    const int*    __restrict__ src,
    const int*    __restrict__ dst,
    float*        __restrict__ acc,     // [kNodes*64] zero-initialized
    float*        __restrict__ deg) {   // [kNodes]    zero-initialized
  int t = blockIdx.x * 256 + threadIdx.x;
  int e = t >> 4;
  if (e >= kEdges) return;
  int lane = t & 15;
  int s = src[e];
  int d = dst[e];
  float4 v = feat4[(size_t)s * 16 + lane];
  float* p = acc + (size_t)d * 64 + lane * 4;
  atomicAdd(p + 0, v.x);
  atomicAdd(p + 1, v.y);
  atomicAdd(p + 2, v.z);
  atomicAdd(p + 3, v.w);
  if (lane == 0) atomicAdd(deg + d, 1.0f);
}

// ---------------------------------------------------------------------------
// Kernel 2: node-parallel mean + linear + relu, in place over acc (=d_out).
// One wave per node (4 nodes / 256-thread block). W staged transposed in LDS
// with +1 padding: compute reads Wt[d*65+lane] are 64 consecutive addresses
// (2 lanes/bank = free), hs[wave][d] is a broadcast (free).
// ---------------------------------------------------------------------------
__global__ __launch_bounds__(256) void gcn_apply(
    float*       __restrict__ acc,   // in: summed rows; out: final output
    const float* __restrict__ deg,
    const float* __restrict__ W,     // [64][64] row-major, W[o][d]
    const float* __restrict__ b) {   // [64]
  __shared__ float Wt[64 * 65];      // Wt[d*65 + o] = W[o*64 + d]
  __shared__ float hs[4][64];

  int tid = threadIdx.x;
  // Stage W transposed (coalesced global reads; one-time LDS writes).
  #pragma unroll
  for (int k = 0; k < 16; ++k) {
    int idx = k * 256 + tid;
    int o = idx >> 6;
    int d = idx & 63;
    Wt[d * 65 + o] = W[idx];
  }

  int wave = tid >> 6;
  int lane = tid & 63;
  int n = blockIdx.x * 4 + wave;

  float h = 0.0f;
  if (n < kNodes) {
    float dg = deg[n];
    dg = dg > 1.0f ? dg : 1.0f;
    h = acc[(size_t)n * 64 + lane] / dg;
  }
  hs[wave][lane] = h;
  __syncthreads();
  if (n >= kNodes) return;

  float sum = b[lane];
  #pragma unroll
  for (int d = 0; d < 64; ++d) {
    sum += hs[wave][d] * Wt[d * 65 + lane];
  }
  acc[(size_t)n * 64 + lane] = sum > 0.0f ? sum : 0.0f;
}

// ---------------------------------------------------------------------------
extern "C" void kernel_launch(void* const* d_in, const int* in_sizes, int n_in,
                              void* d_out, int out_size, void* d_ws, size_t ws_size,
                              hipStream_t stream) {
  const float* feature  = (const float*)d_in[0];   // [100000*64]
  const int*   edge_src = (const int*)  d_in[1];   // [1200000]
  const int*   edge_dst = (const int*)  d_in[2];   // [1200000]
  const float* W        = (const float*)d_in[3];   // [64*64]
  const float* b        = (const float*)d_in[4];   // [64]

  float* out = (float*)d_out;                      // [100000*64], doubles as sum acc
  float* deg = (float*)d_ws;                       // [100000] in workspace

  // Harness poisons d_out / d_ws with 0xAA before every launch: zero them.
  hipMemsetAsync(out, 0, (size_t)kNodes * kFeats * sizeof(float), stream);
  hipMemsetAsync(deg, 0, (size_t)kNodes * sizeof(float), stream);

  // Scatter: 16 threads per edge.
  {
    long long threads = (long long)kEdges * 16;
    int blocks = (int)((threads + 255) / 256);     // 75000
    gcn_scatter<<<blocks, 256, 0, stream>>>(
        (const float4*)feature, edge_src, edge_dst, out, deg);
  }

  // Apply: one wave per node, 4 nodes per block.
  {
    int blocks = (kNodes + 3) / 4;                 // 25000
    gcn_apply<<<blocks, 256, 0, stream>>>(out, deg, W, b);
  }
}

// Round 2
// 547.254 us; speedup vs baseline: 2.2146x; 2.2146x over previous
//
#include <hip/hip_runtime.h>

// GCN layer: out = relu( segment_mean(feature[edge_src], edge_dst) @ W^T + b )
// N=100000 nodes, E=1200000 edges, 64 feats in/out, all f32.
//
// Round 2: replace 76.8M f32 scatter-atomics (atomic-throughput bound, 1078us,
// WRITE_SIZE 1.24GB) with on-the-fly CSR build (2.4M int atomics) + gather-side
// register accumulation.

constexpr int kNodes = 100000;
constexpr int kEdges = 1200000;
constexpr int kFeats = 64;

// Workspace layout (int elements; base is 16B-aligned by harness)
constexpr int kWsCounts = 0;        // [100000]
constexpr int kWsOffsets = 100000;  // [100001]
constexpr int kWsCursor = 200008;   // [100000]
constexpr int kWsSorted = 300008;   // [1200000]
// total ~6.0 MB of d_ws

// ---------------------------------------------------------------------------
// Kernel 1: histogram of destination degrees. 1.2M scattered int atomics.
// ---------------------------------------------------------------------------
__global__ __launch_bounds__(256) void gcn_hist(
    const int* __restrict__ dst, int* __restrict__ counts) {
  int e = blockIdx.x * 256 + threadIdx.x;
  if (e < kEdges) atomicAdd(&counts[dst[e]], 1);
}

// ---------------------------------------------------------------------------
// Kernel 2: exclusive prefix sum over 100K counts, single 1024-thread block.
// Writes offsets[0..N] and a second copy (cursor) for the fill kernel.
// ---------------------------------------------------------------------------
__global__ __launch_bounds__(1024) void gcn_scan(
    const int* __restrict__ counts,
    int* __restrict__ offsets,
    int* __restrict__ cursor) {
  __shared__ int partial[1024];
  const int t = threadIdx.x;
  constexpr int CHUNK = 98;  // 1024*98 = 100352 >= 100000
  int begin = t * CHUNK;
  int end = begin + CHUNK;
  if (end > kNodes) end = kNodes;
  if (begin > kNodes) begin = kNodes;

  int s = 0;
  for (int i = begin; i < end; ++i) s += counts[i];
  partial[t] = s;
  __syncthreads();

  // Hillis-Steele inclusive scan over 1024 partials.
  for (int off = 1; off < 1024; off <<= 1) {
    int v = (t >= off) ? partial[t - off] : 0;
    __syncthreads();
    partial[t] += v;
    __syncthreads();
  }

  int run = (t == 0) ? 0 : partial[t - 1];
  for (int i = begin; i < end; ++i) {
    offsets[i] = run;
    cursor[i] = run;
    run += counts[i];
  }
  if (t == 1023) offsets[kNodes] = partial[1023];
}

// ---------------------------------------------------------------------------
// Kernel 3: scatter edge source-ids into CSR order. 1.2M int atomics.
// ---------------------------------------------------------------------------
__global__ __launch_bounds__(256) void gcn_fill(
    const int* __restrict__ src, const int* __restrict__ dst,
    int* __restrict__ cursor, int* __restrict__ sorted_src) {
  int e = blockIdx.x * 256 + threadIdx.x;
  if (e < kEdges) {
    int pos = atomicAdd(&cursor[dst[e]], 1);
    sorted_src[pos] = src[e];
  }
}

// ---------------------------------------------------------------------------
// Kernel 4: fused gather-mean + linear + relu.
// One wave per node (lane = feature index). Each in-edge is a coalesced 256B
// row read; accumulate in registers (no atomics). Then h -> LDS, out[o=lane]
// = relu(b[o] + sum_d h[d]*W[o][d]) with W transposed+padded in LDS.
// ---------------------------------------------------------------------------
__global__ __launch_bounds__(256) void gcn_gather_apply(
    const float* __restrict__ feature,
    const int*   __restrict__ offsets,
    const int*   __restrict__ sorted_src,
    const float* __restrict__ W,     // [64][64] row-major W[o][d]
    const float* __restrict__ b,     // [64]
    float*       __restrict__ out) { // [kNodes][64]
  __shared__ float Wt[64 * 65];      // Wt[d*65+o] = W[o*64+d]
  __shared__ float hs[4][64];

  const int tid = threadIdx.x;
  #pragma unroll
  for (int k = 0; k < 16; ++k) {
    int idx = k * 256 + tid;
    Wt[(idx & 63) * 65 + (idx >> 6)] = W[idx];
  }

  const int wave = tid >> 6;
  const int lane = tid & 63;
  const int n = blockIdx.x * 4 + wave;

  float h = 0.0f;
  if (n < kNodes) {
    const int o0 = offsets[n];
    const int o1 = offsets[n + 1];
    float sum0 = 0.0f, sum1 = 0.0f;
    int j = o0;
    for (; j + 1 < o1; j += 2) {          // 2-deep to overlap dependent loads
      int s0 = sorted_src[j];
      int s1 = sorted_src[j + 1];
      sum0 += feature[(size_t)s0 * 64 + lane];
      sum1 += feature[(size_t)s1 * 64 + lane];
    }
    if (j < o1) sum0 += feature[(size_t)sorted_src[j] * 64 + lane];
    int dg = o1 - o0;
    h = (sum0 + sum1) / (float)(dg > 1 ? dg : 1);
  }
  hs[wave][lane] = h;
  __syncthreads();

  if (n < kNodes) {
    float acc = b[lane];
    #pragma unroll
    for (int d = 0; d < 64; ++d) acc += hs[wave][d] * Wt[d * 65 + lane];
    out[(size_t)n * 64 + lane] = acc > 0.0f ? acc : 0.0f;
  }
}

// ---------------------------------------------------------------------------
extern "C" void kernel_launch(void* const* d_in, const int* in_sizes, int n_in,
                              void* d_out, int out_size, void* d_ws, size_t ws_size,
                              hipStream_t stream) {
  const float* feature  = (const float*)d_in[0];
  const int*   edge_src = (const int*)  d_in[1];
  const int*   edge_dst = (const int*)  d_in[2];
  const float* W        = (const float*)d_in[3];
  const float* b        = (const float*)d_in[4];

  float* out = (float*)d_out;
  int* ws_i = (int*)d_ws;
  int* counts     = ws_i + kWsCounts;
  int* offsets    = ws_i + kWsOffsets;
  int* cursor     = ws_i + kWsCursor;
  int* sorted_src = ws_i + kWsSorted;

  // Harness re-poisons d_ws each call: zero the histogram.
  hipMemsetAsync(counts, 0, (size_t)kNodes * sizeof(int), stream);

  {
    int blocks = (kEdges + 255) / 256;  // 4688
    gcn_hist<<<blocks, 256, 0, stream>>>(edge_dst, counts);
  }

  gcn_scan<<<1, 1024, 0, stream>>>(counts, offsets, cursor);

  {
    int blocks = (kEdges + 255) / 256;
    gcn_fill<<<blocks, 256, 0, stream>>>(edge_src, edge_dst, cursor, sorted_src);
  }

  {
    int blocks = (kNodes + 3) / 4;      // 25000
    gcn_gather_apply<<<blocks, 256, 0, stream>>>(
        feature, offsets, sorted_src, W, b, out);
  }
}

// Round 3
// 300.074 us; speedup vs baseline: 4.0388x; 1.8237x over previous
//
#include <hip/hip_runtime.h>

// GCN layer: out = relu( segment_mean(feature[edge_src], edge_dst) @ W^T + b )
// N=100000 nodes, E=1200000 edges, 64 feats in/out, all f32.
//
// Round 3: single-block scan (230us, 0.15% occupancy, uncoalesced) replaced by
// reduce-then-scan over 98 blocks; gather unroll 2 -> 4.

constexpr int kNodes = 100000;
constexpr int kEdges = 1200000;
constexpr int kFeats = 64;

// Workspace layout (int elements; base 16B-aligned)
constexpr int kWsCounts    = 0;        // [100000]
constexpr int kWsOffsets   = 100000;   // [100001]
constexpr int kWsCursor    = 200008;   // [100000]
constexpr int kWsSorted    = 300008;   // [1200000]
constexpr int kWsBlockSums = 1500008;  // [128]

constexpr int kScanBlocks = (kNodes + 1023) / 1024;  // 98

// ---------------------------------------------------------------------------
// Kernel 1: histogram of destination degrees. 1.2M scattered int atomics.
// ---------------------------------------------------------------------------
__global__ __launch_bounds__(256) void gcn_hist(
    const int* __restrict__ dst, int* __restrict__ counts) {
  int e = blockIdx.x * 256 + threadIdx.x;
  if (e < kEdges) atomicAdd(&counts[dst[e]], 1);
}

// ---------------------------------------------------------------------------
// Kernel 2a: per-block sums of counts (1024 elems/block, int4 loads).
// ---------------------------------------------------------------------------
__global__ __launch_bounds__(256) void gcn_scan_reduce(
    const int* __restrict__ counts, int* __restrict__ blocksums) {
  __shared__ int sm[256];
  const int t = threadIdx.x;
  const int base = blockIdx.x * 1024 + t * 4;
  int s = 0;
  if (base + 3 < kNodes) {
    int4 v = *(const int4*)(counts + base);
    s = v.x + v.y + v.z + v.w;
  } else {
    for (int i = 0; i < 4; ++i)
      if (base + i < kNodes) s += counts[base + i];
  }
  sm[t] = s;
  __syncthreads();
  for (int off = 128; off > 0; off >>= 1) {
    if (t < off) sm[t] += sm[t + off];
    __syncthreads();
  }
  if (t == 0) blocksums[blockIdx.x] = sm[0];
}

// ---------------------------------------------------------------------------
// Kernel 2b: exclusive scan of the 98 block sums (1 block, 128 threads).
// Also writes offsets[kNodes] = total.
// ---------------------------------------------------------------------------
__global__ __launch_bounds__(128) void gcn_scan_top(
    int* __restrict__ blocksums, int* __restrict__ offsets) {
  __shared__ int sm[128];
  const int t = threadIdx.x;
  int s = (t < kScanBlocks) ? blocksums[t] : 0;
  sm[t] = s;
  __syncthreads();
  for (int off = 1; off < 128; off <<= 1) {
    int v = (t >= off) ? sm[t - off] : 0;
    __syncthreads();
    sm[t] += v;
    __syncthreads();
  }
  if (t < kScanBlocks) blocksums[t] = sm[t] - s;  // exclusive
  if (t == 127) offsets[kNodes] = sm[127];        // total (=kEdges)
}

// ---------------------------------------------------------------------------
// Kernel 2c: full exclusive scan: block-local scan + scanned block base.
// Writes offsets[i] and cursor[i].
// ---------------------------------------------------------------------------
__global__ __launch_bounds__(256) void gcn_scan_apply(
    const int* __restrict__ counts, const int* __restrict__ blocksums,
    int* __restrict__ offsets, int* __restrict__ cursor) {
  __shared__ int sm[256];
  const int t = threadIdx.x;
  const int base = blockIdx.x * 1024 + t * 4;

  int v0 = 0, v1 = 0, v2 = 0, v3 = 0;
  if (base + 3 < kNodes) {
    int4 v = *(const int4*)(counts + base);
    v0 = v.x; v1 = v.y; v2 = v.z; v3 = v.w;
  } else {
    if (base + 0 < kNodes) v0 = counts[base + 0];
    if (base + 1 < kNodes) v1 = counts[base + 1];
    if (base + 2 < kNodes) v2 = counts[base + 2];
    if (base + 3 < kNodes) v3 = counts[base + 3];
  }
  const int s = v0 + v1 + v2 + v3;
  sm[t] = s;
  __syncthreads();
  for (int off = 1; off < 256; off <<= 1) {
    int v = (t >= off) ? sm[t - off] : 0;
    __syncthreads();
    sm[t] += v;
    __syncthreads();
  }
  int run = blocksums[blockIdx.x] + sm[t] - s;  // exclusive base for this thread

  if (base + 0 < kNodes) { offsets[base + 0] = run; cursor[base + 0] = run; run += v0; }
  if (base + 1 < kNodes) { offsets[base + 1] = run; cursor[base + 1] = run; run += v1; }
  if (base + 2 < kNodes) { offsets[base + 2] = run; cursor[base + 2] = run; run += v2; }
  if (base + 3 < kNodes) { offsets[base + 3] = run; cursor[base + 3] = run; }
}

// ---------------------------------------------------------------------------
// Kernel 3: scatter edge source-ids into CSR order. 1.2M int atomics.
// ---------------------------------------------------------------------------
__global__ __launch_bounds__(256) void gcn_fill(
    const int* __restrict__ src, const int* __restrict__ dst,
    int* __restrict__ cursor, int* __restrict__ sorted_src) {
  int e = blockIdx.x * 256 + threadIdx.x;
  if (e < kEdges) {
    int pos = atomicAdd(&cursor[dst[e]], 1);
    sorted_src[pos] = src[e];
  }
}

// ---------------------------------------------------------------------------
// Kernel 4: fused gather-mean + linear + relu. One wave per node.
// 4-deep unrolled gather for memory-level parallelism.
// ---------------------------------------------------------------------------
__global__ __launch_bounds__(256) void gcn_gather_apply(
    const float* __restrict__ feature,
    const int*   __restrict__ offsets,
    const int*   __restrict__ sorted_src,
    const float* __restrict__ W,     // [64][64] row-major W[o][d]
    const float* __restrict__ b,     // [64]
    float*       __restrict__ out) { // [kNodes][64]
  __shared__ float Wt[64 * 65];      // Wt[d*65+o] = W[o*64+d]
  __shared__ float hs[4][64];

  const int tid = threadIdx.x;
  #pragma unroll
  for (int k = 0; k < 16; ++k) {
    int idx = k * 256 + tid;
    Wt[(idx & 63) * 65 + (idx >> 6)] = W[idx];
  }

  const int wave = tid >> 6;
  const int lane = tid & 63;
  const int n = blockIdx.x * 4 + wave;

  float h = 0.0f;
  if (n < kNodes) {
    const int o0 = offsets[n];
    const int o1 = offsets[n + 1];
    float s0 = 0.f, s1 = 0.f, s2 = 0.f, s3 = 0.f;
    int j = o0;
    for (; j + 3 < o1; j += 4) {
      int a = sorted_src[j], bI = sorted_src[j + 1];
      int c = sorted_src[j + 2], d = sorted_src[j + 3];
      s0 += feature[(size_t)a  * 64 + lane];
      s1 += feature[(size_t)bI * 64 + lane];
      s2 += feature[(size_t)c  * 64 + lane];
      s3 += feature[(size_t)d  * 64 + lane];
    }
    for (; j < o1; ++j) s0 += feature[(size_t)sorted_src[j] * 64 + lane];
    int dg = o1 - o0;
    h = ((s0 + s1) + (s2 + s3)) / (float)(dg > 1 ? dg : 1);
  }
  hs[wave][lane] = h;
  __syncthreads();

  if (n < kNodes) {
    float acc = b[lane];
    #pragma unroll
    for (int d = 0; d < 64; ++d) acc += hs[wave][d] * Wt[d * 65 + lane];
    out[(size_t)n * 64 + lane] = acc > 0.0f ? acc : 0.0f;
  }
}

// ---------------------------------------------------------------------------
extern "C" void kernel_launch(void* const* d_in, const int* in_sizes, int n_in,
                              void* d_out, int out_size, void* d_ws, size_t ws_size,
                              hipStream_t stream) {
  const float* feature  = (const float*)d_in[0];
  const int*   edge_src = (const int*)  d_in[1];
  const int*   edge_dst = (const int*)  d_in[2];
  const float* W        = (const float*)d_in[3];
  const float* b        = (const float*)d_in[4];

  float* out = (float*)d_out;
  int* ws_i = (int*)d_ws;
  int* counts     = ws_i + kWsCounts;
  int* offsets    = ws_i + kWsOffsets;
  int* cursor     = ws_i + kWsCursor;
  int* sorted_src = ws_i + kWsSorted;
  int* blocksums  = ws_i + kWsBlockSums;

  hipMemsetAsync(counts, 0, (size_t)kNodes * sizeof(int), stream);

  gcn_hist<<<(kEdges + 255) / 256, 256, 0, stream>>>(edge_dst, counts);

  gcn_scan_reduce<<<kScanBlocks, 256, 0, stream>>>(counts, blocksums);
  gcn_scan_top<<<1, 128, 0, stream>>>(blocksums, offsets);
  gcn_scan_apply<<<kScanBlocks, 256, 0, stream>>>(counts, blocksums, offsets, cursor);

  gcn_fill<<<(kEdges + 255) / 256, 256, 0, stream>>>(edge_src, edge_dst, cursor, sorted_src);

  gcn_gather_apply<<<(kNodes + 3) / 4, 256, 0, stream>>>(
      feature, offsets, sorted_src, W, b, out);
}